// Round 7
// baseline (688.001 us; speedup 1.0000x reference)
//
#include <hip/hip_runtime.h>
#include <hip/hip_bf16.h>

typedef unsigned short ushort_t;
typedef unsigned int uint_t;

#define KL 1024
#define IL 8192
#define DIMV 128
#define NS 16
#define NB 258               // 32-col blocks per strip (258*32 = 8256 skewed steps)
#define NIT2 270             // even iteration count (covers export i=267 / publish i=268)
#define SSH (8256*64)        // ushorts per strip of c_h (fp16, pair-packed)
#define GATE 416             // cross-wg start cushion: 13 blocks * 32 cols
#define INF __builtin_inff()

typedef __attribute__((ext_vector_type(8))) short v8s;   // bf16x8 MFMA A/B frag
typedef __attribute__((ext_vector_type(4))) float v4f;   // MFMA C/D frag

// ---------------- kernel 1: squared row norms + zero flags ----------------
__global__ __launch_bounds__(256) void knorms(
    const float* __restrict__ kern, const float* __restrict__ xx,
    float* __restrict__ x2, float* __restrict__ k2, int* __restrict__ flags) {
  if (blockIdx.x == 0 && threadIdx.x < NS) flags[threadIdx.x] = 0;
  const int lane = threadIdx.x & 63;
  const int row = blockIdx.x * 4 + (threadIdx.x >> 6);
  const float* src;
  float* dst;
  if (row < IL) { src = xx + (size_t)row * DIMV; dst = x2 + row; }
  else          { src = kern + (size_t)(row - IL) * DIMV; dst = k2 + (row - IL); }
  float2 v = *(const float2*)(src + lane * 2);
  float ss = v.x * v.x + v.y * v.y;
  #pragma unroll
  for (int off = 32; off > 0; off >>= 1) ss += __shfl_down(ss, off, 64);
  if (lane == 0) *dst = ss;
}

// ---------------- kernel 2: MFMA bf16 GEMM -> c (fp16), lane-major block layout ----
// Layout: strip s, block b (32 cols), uint index = b*1024 + lane*16 + tpl
// where lane = row-within-strip (dk), tpl = (t>>1)&15, fp16 pair select = t&1.
// Each kdp lane then reads its 16 uints for a block as 64 contiguous bytes.
__device__ __forceinline__ v8s pack_bf16x8(float4 a, float4 b) {
  union { unsigned int u[4]; v8s v; } r;
  union { __hip_bfloat162 h; unsigned int u; } t;
  t.h = __float22bfloat162_rn(make_float2(a.x, a.y)); r.u[0] = t.u;
  t.h = __float22bfloat162_rn(make_float2(a.z, a.w)); r.u[1] = t.u;
  t.h = __float22bfloat162_rn(make_float2(b.x, b.y)); r.u[2] = t.u;
  t.h = __float22bfloat162_rn(make_float2(b.z, b.w)); r.u[3] = t.u;
  return r.v;
}

__global__ __launch_bounds__(256) void kgemm(
    const float* __restrict__ kern, const float* __restrict__ xx,
    const float* __restrict__ x2, const float* __restrict__ k2,
    ushort_t* __restrict__ c_h) {
  __shared__ float ctile[64 * 64];   // [n=x-col][m-swizzled]
  const int T = threadIdx.x;
  const int w = T >> 6;
  const int lane = T & 63;
  const int lo = lane & 15;
  const int hi = lane >> 4;
  const int i0 = blockIdx.x * 64;    // DTW columns (x rows)
  const int s  = blockIdx.y;         // strip
  const int kr0 = s * 64;

  v4f acc[4] = {};
  #pragma unroll
  for (int ks = 0; ks < 4; ks++) {
    const int k = ks * 32 + hi * 8;
    const float* bp = xx + (size_t)(i0 + w * 16 + lo) * DIMV + k;
    v8s bf = pack_bf16x8(*(const float4*)bp, *(const float4*)(bp + 4));
    #pragma unroll
    for (int rt = 0; rt < 4; rt++) {
      const float* ap = kern + (size_t)(kr0 + rt * 16 + lo) * DIMV + k;
      v8s af = pack_bf16x8(*(const float4*)ap, *(const float4*)(ap + 4));
      acc[rt] = __builtin_amdgcn_mfma_f32_16x16x32_bf16(af, bf, acc[rt], 0, 0, 0);
    }
  }
  const float x2v = x2[i0 + w * 16 + lo];
  const int n_local = w * 16 + lo;
  #pragma unroll
  for (int rt = 0; rt < 4; rt++) {
    float4 k2f = *(const float4*)&k2[kr0 + rt * 16 + hi * 4];
    #pragma unroll
    for (int q = 0; q < 4; q++) {
      const int m_local = rt * 16 + hi * 4 + q;
      float cval = fmaxf((&k2f.x)[q] + x2v - 2.f * acc[rt][q], 0.f);
      ctile[n_local * 64 + ((m_local + 2 * n_local) & 63)] = cval;
    }
  }
  __syncthreads();
  // skew-scatter as fp16 pairs: element (t = i0+tt, lane=dk), lane-major layout
  _Float16* ob = (_Float16*)(c_h + (size_t)s * SSH);
  #pragma unroll
  for (int q = 0; q < 32; q++) {
    int tt = w + q * 4;              // local skewed row in [0,126]
    int di = tt - lane;
    if (tt <= 126 && di >= 0 && di < 64) {
      int t = i0 + tt;
      int tp = t >> 1;
      ob[(((size_t)(tp >> 4) * 1024) + lane * 16 + (tp & 15)) * 2 + (t & 1)] =
          (_Float16)ctile[di * 64 + ((lane + 2 * di) & 63)];
    }
  }
}

// ---------------- kernel 3: 4 strips per workgroup, 5 waves, lag-3 pipeline ----------------
// This revision: 2-column lookahead in the interior fast path to halve the exposure of
// the cross-lane shift latency (the measured ~66 cy/col invariant across R0-R6).
// Recurrence: D_t[m] = c_t[m] + min(D_{t-1}[m], D_{t-1}[m-1], D_{t-2}[m-1]).
// Double step with X=D_{u-1}, y1=D_{u-2}[m-1], y2=D_{u-2}[m-2]:
//   x1 = shr1(X) (DPP), x2 = X[m-2] (ds_bpermute, PARALLEL with x1)
//   D_u     = c_u     + min(X, x1, y1)
//   E       = c_u[m-1] + min(x1, x2, y2)   (lane0 -> fv[u+1]); E == D_u[m-1]
//   D_{u+1} = c_{u+1} + min(D_u, x1, E)
//   z1 = shr1(D_u), z2 = D_u[m-2] (bpermute) -> next step's y1,y2 (one step of slack)
// Boundary semantics: D_s[-1] = fv[s+1]; all holes verified (x1/x2 <- fv[u],
// z1/z2 <- fv[u+1], lane0 E-override <- fv[u+1]). Guard blocks (W<2, W>=256) keep
// the original single-step loop; bridges: exit y1=Dul (definitionally equal),
// y2=shr1(Dul) (lane1 auto-correct: Dul[0] already holds the boundary).
__device__ __forceinline__ float dpp_wave_shr1(float oldv, float src) {
  return __int_as_float(__builtin_amdgcn_update_dpp(
      __float_as_int(oldv), __float_as_int(src), 0x138, 0xF, 0xF, false));
}
__device__ __forceinline__ float bperm_f(int idx_bytes, float v) {
  return __int_as_float(__builtin_amdgcn_ds_bpermute(idx_bytes, __float_as_int(v)));
}

__global__ __launch_bounds__(320, 1) void kdp(
    const ushort_t* __restrict__ c_h, float* __restrict__ bound,
    int* __restrict__ flags, float* __restrict__ out) {
  __shared__ __align__(16) float ring[4 * 4 * 32];   // wave k out-ring: ring + k*128
  __shared__ __align__(16) float feed[4 * 32];       // sync -> wave0 feed ring
  const int g = blockIdx.x;
  const int wv = threadIdx.x >> 6;        // 0..3 DP, 4 sync
  const int lane = threadIdx.x & 63;
  const int sb = g * 4;

  float X = INF, y1 = INF, y2 = INF;      // X=D_{t-1}; y1=D_{t-2}[m-1]; y2=D_{t-2}[m-2]
  int fchk = 0, fpend = 0;
  float rfeed = INF;
  const float* bin = bound + (size_t)(sb > 0 ? sb - 1 : 0) * IL;
  float* bout3 = bound + (size_t)(sb + 3) * IL;
  const int bpi2 = ((lane - 2) & 63) << 2;           // bpermute byte index: lane-2

  // per-DP-wave global base for this strip (lane-major layout)
  const uint_t* cbase = (const uint_t*)c_h +
      (size_t)(sb + (wv < 4 ? wv : 0)) * (SSH / 2) + lane * 16;

  uint_t P[16], Q[16];

  // ---- pre-loop ----
  if (wv < 4) {
    const uint4* sp = (const uint4*)cbase;
    *(uint4*)&P[0] = sp[0]; *(uint4*)&P[4] = sp[1];
    *(uint4*)&P[8] = sp[2]; *(uint4*)&P[12] = sp[3];
    if (g == 0 && wv == 0 && lane == 0) X = 0.f;
  } else {
    if (g > 0) {
      int f;
      do { f = __hip_atomic_load(&flags[sb - 1], __ATOMIC_RELAXED, __HIP_MEMORY_SCOPE_AGENT); } while (f < GATE);
      fchk = f; fpend = f;
      if (lane < 32) {
        feed[lane]      = __hip_atomic_load(&bin[lane],      __ATOMIC_RELAXED, __HIP_MEMORY_SCOPE_AGENT);
        feed[32 + lane] = __hip_atomic_load(&bin[32 + lane], __ATOMIC_RELAXED, __HIP_MEMORY_SCOPE_AGENT);
        rfeed           = __hip_atomic_load(&bin[64 + lane], __ATOMIC_RELAXED, __HIP_MEMORY_SCOPE_AGENT);
      }
    } else {
      if (lane < 32) { feed[lane] = INF; feed[32+lane] = INF; feed[64+lane] = INF; feed[96+lane] = INF; }
    }
  }
  __syncthreads();   // full drain once; P resident, feed initialized

  auto body = [&](int i, uint_t (&cur)[16], uint_t (&nxt)[16]) {
    if (wv < 4) {
      // ---- DP wave k = wv, strip sb+k, block W = i - 3k (lag 3) ----
      const int W = i - 3 * wv;
      // depth-1 prefetch of block W+1 (clamped; always 4 loads, used NEXT iter)
      int Wn = W + 1; Wn = Wn < 0 ? 0 : (Wn > NB - 1 ? NB - 1 : Wn);
      {
        const uint4* sp = (const uint4*)(cbase + (size_t)Wn * 1024);
        *(uint4*)&nxt[0]  = sp[0]; *(uint4*)&nxt[4]  = sp[1];
        *(uint4*)&nxt[8]  = sp[2]; *(uint4*)&nxt[12] = sp[3];
      }
      if (W >= 0 && W < NB) {
        // boundary values: fv[tt] = boundary for col 32W+tt (D_s[-1] = fv[s+1])
        const float* fb = (wv == 0) ? &feed[(W & 3) * 32]
                                    : &ring[(wv - 1) * 128 + (W & 3) * 32];
        float fv[32];
        #pragma unroll
        for (int q = 0; q < 8; q++) {
          float4 f4 = *(const float4*)(fb + q * 4);
          fv[4 * q]     = f4.x; fv[4 * q + 1] = f4.y;
          fv[4 * q + 2] = f4.z; fv[4 * q + 3] = f4.w;
        }
        float cvv[32];
        #pragma unroll
        for (int tp = 0; tp < 16; tp++) {
          union { uint_t u; _Float16 h[2]; } cu; cu.u = cur[tp];
          cvv[2 * tp]     = (float)cu.h[0];
          cvv[2 * tp + 1] = (float)cu.h[1];
        }
        float bb[32];                       // lane63's per-step D values
        if (W >= 2 && W < 256) {
          // c_u[m-1] for even cols (lane0 slot unused: E overridden there)
          float cs[16];
          #pragma unroll
          for (int p = 0; p < 16; p++) cs[p] = dpp_wave_shr1(cvv[2 * p], cvv[2 * p]);
          #pragma unroll
          for (int p = 0; p < 16; p++) {
            const int u = 2 * p;
            float x1 = dpp_wave_shr1(fv[u], X);          // X[m-1], lane0<-fv[u]
            float x2 = bperm_f(bpi2, X);                 // X[m-2] (parallel with x1)
            x2 = (lane < 2) ? fv[u] : x2;                // lane1<-fv[u]; lane0 dc
            float Du = cvv[u] + fminf(fminf(X, x1), y1);
            float E  = cs[p] + fminf(fminf(x1, y2), x2); // == D_u[m-1] for lane>0
            E = (lane == 0) ? fv[u + 1] : E;
            float Du1 = cvv[u + 1] + fminf(fminf(Du, x1), E);
            float z1 = dpp_wave_shr1(fv[u + 1], Du);     // D_u[m-1] -> next y1
            float z2 = bperm_f(bpi2, Du);                // D_u[m-2] -> next y2
            z2 = (lane < 2) ? fv[u + 1] : z2;
            bb[u] = Du; bb[u + 1] = Du1;
            X = Du1; y1 = z1; y2 = z2;
          }
        } else {
          // guarded single-step path (blocks 0,1,256,257) — original loop,
          // X==Dcur, y1==Dul
          const int t0 = W * 32;
          #pragma unroll
          for (int tt = 0; tt < 32; tt++) {
            const int t = t0 + tt;
            float Dup = dpp_wave_shr1(fv[tt], X);
            float m1 = fminf(y1, X);
            float Dnew = cvv[tt] + fminf(m1, Dup);
            const bool alo = (t >= lane);          // j >= 0
            const bool ahi = (t - lane < IL);      // j < IL
            if (alo) y1 = Dup;
            if (alo && ahi) X = Dnew;
            bb[tt] = X;
          }
          // bridge to double-step state: y2[m] = D_{T-1}[m-2] = y1[m-1];
          // lane1 auto-correct (y1[0] holds the boundary), lane0 dc
          y2 = dpp_wave_shr1(y1, y1);
        }
        // ring write: lane63's bottom-row values (verified mapping:
        // step tt -> col 32(W-2)+tt+1 -> slot W-2 pos tt+1 (tt<=30, W>=2);
        // tt=31 -> slot W-1 pos 0 (W>=1))
        if (lane == 63) {
          const int base2 = wv * 128 + (((W - 2) & 3) << 5);
          const int base1 = wv * 128 + (((W - 1) & 3) << 5);
          if (W >= 2) {
            #pragma unroll
            for (int tt = 0; tt < 31; tt++) ring[base2 + tt + 1] = bb[tt];
          }
          if (W >= 1) ring[base1] = bb[31];
        }
      }
      asm volatile("s_waitcnt lgkmcnt(0)" ::: "memory");  // ring writes visible
      __builtin_amdgcn_s_barrier();
    } else {
      // ---- sync wave ----
      asm volatile("s_waitcnt vmcnt(0)" ::: "memory");    // prev-iter ops (one period old)
      if (g > 0) {
        if (fpend > fchk) fchk = fpend;           // consume last iter's flag load
        const int Fw = i + 2;                     // ds_write feed loaded last iter
        if (Fw >= 2 && Fw <= 255 && lane < 32) feed[(Fw & 3) * 32 + lane] = rfeed;
        const int Fl = i + 3;                     // issue next feed load
        if (Fl <= 255) {
          const int need = 32 * (Fl + 1);
          if (fchk < need) {                      // rare (cushion covers steady state)
            int f;
            do { f = __hip_atomic_load(&flags[sb - 1], __ATOMIC_RELAXED, __HIP_MEMORY_SCOPE_AGENT); } while (f < need);
            fchk = f;
          }
          if (lane < 32)
            rfeed = __hip_atomic_load(&bin[32 * Fl + lane], __ATOMIC_RELAXED, __HIP_MEMORY_SCOPE_AGENT);
        }
        fpend = __hip_atomic_load(&flags[sb - 1], __ATOMIC_RELAXED, __HIP_MEMORY_SCOPE_AGENT);
      }
      if (g < 3) {
        const int E = i - 12;                     // export wave3's boundary block E
        if (E >= 0 && E < 256 && lane < 32) {
          float bv2 = ring[3 * 128 + (E & 3) * 32 + lane];
          __hip_atomic_store(&bout3[32 * E + lane], bv2, __ATOMIC_RELAXED, __HIP_MEMORY_SCOPE_AGENT);
        }
        const int Ep = i - 13;                    // publish E-1's export (drained at iter start)
        if (Ep >= 0 && Ep < 256 && lane == 0)
          __hip_atomic_store(&flags[sb + 3], 32 * Ep + 32, __ATOMIC_RELAXED, __HIP_MEMORY_SCOPE_AGENT);
      }
      asm volatile("s_waitcnt lgkmcnt(0)" ::: "memory");  // publish feed ds_write
      __builtin_amdgcn_s_barrier();
    }
  };

  for (int i = 0; i < NIT2; i += 2) {
    body(i, P, Q);
    body(i + 1, Q, P);
  }

  asm volatile("s_waitcnt vmcnt(0)" ::: "memory");  // quiesce before endpgm
  if (g == 3 && wv == 3 && lane == 63) out[0] = X;  // D[K-1][I-1] == optimal path sum
}

extern "C" void kernel_launch(void* const* d_in, const int* in_sizes, int n_in,
                              void* d_out, int out_size, void* d_ws, size_t ws_size,
                              hipStream_t stream) {
  const float* kern = (const float*)d_in[0]; // (1024,128)
  const float* xx   = (const float*)d_in[1]; // (8192,128)
  char* ws = (char*)d_ws;
  const size_t OFF_X2 = (size_t)NS * SSH * 2;           // c_h: ~16.9 MB
  const size_t OFF_K2 = OFF_X2 + (size_t)IL * 4;
  const size_t OFF_BD = OFF_K2 + (size_t)KL * 4;
  const size_t OFF_FL = OFF_BD + (size_t)NS * IL * 4;
  ushort_t* c_h  = (ushort_t*)ws;
  float* x2    = (float*)(ws + OFF_X2);
  float* k2    = (float*)(ws + OFF_K2);
  float* bnd   = (float*)(ws + OFF_BD);
  int*   flags = (int*)(ws + OFF_FL);

  knorms<<<(IL + KL) / 4, 256, 0, stream>>>(kern, xx, x2, k2, flags);
  kgemm<<<dim3(IL / 64, NS), 256, 0, stream>>>(kern, xx, x2, k2, c_h);
  kdp<<<4, 320, 0, stream>>>(c_h, bnd, flags, (float*)d_out);
}

// Round 8
// 445.064 us; speedup vs baseline: 1.5458x; 1.5458x over previous
//
#include <hip/hip_runtime.h>
#include <hip/hip_bf16.h>

typedef unsigned short ushort_t;
typedef unsigned int uint_t;

#define KL 1024
#define IL 8192
#define DIMV 128
#define NS 16
#define NB 258               // 32-col blocks per strip (258*32 = 8256 skewed steps)
#define NIT2 270             // even iteration count (covers export i=267 / publish i=268)
#define SSH (8256*64)        // ushorts per strip of c_h (fp16, pair-packed)
#define GATE 416             // cross-wg start cushion: 13 blocks * 32 cols
#define INF __builtin_inff()

typedef __attribute__((ext_vector_type(8))) short v8s;   // bf16x8 MFMA A/B frag
typedef __attribute__((ext_vector_type(4))) float v4f;   // MFMA C/D frag

// ---------------- kernel 1: squared row norms + zero flags ----------------
__global__ __launch_bounds__(256) void knorms(
    const float* __restrict__ kern, const float* __restrict__ xx,
    float* __restrict__ x2, float* __restrict__ k2, int* __restrict__ flags) {
  if (blockIdx.x == 0 && threadIdx.x < NS) flags[threadIdx.x] = 0;
  const int lane = threadIdx.x & 63;
  const int row = blockIdx.x * 4 + (threadIdx.x >> 6);
  const float* src;
  float* dst;
  if (row < IL) { src = xx + (size_t)row * DIMV; dst = x2 + row; }
  else          { src = kern + (size_t)(row - IL) * DIMV; dst = k2 + (row - IL); }
  float2 v = *(const float2*)(src + lane * 2);
  float ss = v.x * v.x + v.y * v.y;
  #pragma unroll
  for (int off = 32; off > 0; off >>= 1) ss += __shfl_down(ss, off, 64);
  if (lane == 0) *dst = ss;
}

// ---------------- kernel 2: MFMA bf16 GEMM -> c (fp16), lane-major block layout ----
// Layout: strip s, block b (32 cols), uint index = b*1024 + lane*16 + tpl
// where lane = row-within-strip (dk), tpl = (t>>1)&15, fp16 pair select = t&1.
// Each kdp lane then reads its 16 uints for a block as 64 contiguous bytes.
__device__ __forceinline__ v8s pack_bf16x8(float4 a, float4 b) {
  union { unsigned int u[4]; v8s v; } r;
  union { __hip_bfloat162 h; unsigned int u; } t;
  t.h = __float22bfloat162_rn(make_float2(a.x, a.y)); r.u[0] = t.u;
  t.h = __float22bfloat162_rn(make_float2(a.z, a.w)); r.u[1] = t.u;
  t.h = __float22bfloat162_rn(make_float2(b.x, b.y)); r.u[2] = t.u;
  t.h = __float22bfloat162_rn(make_float2(b.z, b.w)); r.u[3] = t.u;
  return r.v;
}

__global__ __launch_bounds__(256) void kgemm(
    const float* __restrict__ kern, const float* __restrict__ xx,
    const float* __restrict__ x2, const float* __restrict__ k2,
    ushort_t* __restrict__ c_h) {
  __shared__ float ctile[64 * 64];   // [n=x-col][m-swizzled]
  const int T = threadIdx.x;
  const int w = T >> 6;
  const int lane = T & 63;
  const int lo = lane & 15;
  const int hi = lane >> 4;
  const int i0 = blockIdx.x * 64;    // DTW columns (x rows)
  const int s  = blockIdx.y;         // strip
  const int kr0 = s * 64;

  v4f acc[4] = {};
  #pragma unroll
  for (int ks = 0; ks < 4; ks++) {
    const int k = ks * 32 + hi * 8;
    const float* bp = xx + (size_t)(i0 + w * 16 + lo) * DIMV + k;
    v8s bf = pack_bf16x8(*(const float4*)bp, *(const float4*)(bp + 4));
    #pragma unroll
    for (int rt = 0; rt < 4; rt++) {
      const float* ap = kern + (size_t)(kr0 + rt * 16 + lo) * DIMV + k;
      v8s af = pack_bf16x8(*(const float4*)ap, *(const float4*)(ap + 4));
      acc[rt] = __builtin_amdgcn_mfma_f32_16x16x32_bf16(af, bf, acc[rt], 0, 0, 0);
    }
  }
  const float x2v = x2[i0 + w * 16 + lo];
  const int n_local = w * 16 + lo;
  #pragma unroll
  for (int rt = 0; rt < 4; rt++) {
    float4 k2f = *(const float4*)&k2[kr0 + rt * 16 + hi * 4];
    #pragma unroll
    for (int q = 0; q < 4; q++) {
      const int m_local = rt * 16 + hi * 4 + q;
      float cval = fmaxf((&k2f.x)[q] + x2v - 2.f * acc[rt][q], 0.f);
      ctile[n_local * 64 + ((m_local + 2 * n_local) & 63)] = cval;
    }
  }
  __syncthreads();
  // skew-scatter as fp16 pairs: element (t = i0+tt, lane=dk), lane-major layout
  _Float16* ob = (_Float16*)(c_h + (size_t)s * SSH);
  #pragma unroll
  for (int q = 0; q < 32; q++) {
    int tt = w + q * 4;              // local skewed row in [0,126]
    int di = tt - lane;
    if (tt <= 126 && di >= 0 && di < 64) {
      int t = i0 + tt;
      int tp = t >> 1;
      ob[(((size_t)(tp >> 4) * 1024) + lane * 16 + (tp & 15)) * 2 + (t & 1)] =
          (_Float16)ctile[di * 64 + ((lane + 2 * di) & 63)];
    }
  }
}

// ---------------- kernel 3: 4 strips per workgroup, 5 waves, lag-3 pipeline ----------------
// This revision vs R5 (311 us): fixes the in-period VMEM stall. Previous versions issued
// the next-block prefetch (via *(uint4*)& punning into a local array) IMMEDIATELY BEFORE
// unpacking the current block; conservative aliasing forces s_waitcnt vmcnt(0) on the
// just-issued loads -> ~1-1.5k cy cross-XCD read latency inside EVERY period (the
// measured ~1600cy/period stall; VALU issue is only ~500cy). Fix: (a) P/Q are honest
// uint4[4] arrays, component access only, no pointer punning; (b) body order is
// unpack-cur FIRST, prefetch-nxt AFTER -> any wait before unpack refers to loads
// issued a full period earlier (~1800cy slack). Chain = exact R5 single-step.
__device__ __forceinline__ float dpp_wave_shr1(float oldv, float src) {
  return __int_as_float(__builtin_amdgcn_update_dpp(
      __float_as_int(oldv), __float_as_int(src), 0x138, 0xF, 0xF, false));
}

__global__ __launch_bounds__(320, 1) void kdp(
    const ushort_t* __restrict__ c_h, float* __restrict__ bound,
    int* __restrict__ flags, float* __restrict__ out) {
  __shared__ __align__(16) float ring[4 * 4 * 32];   // wave k out-ring: ring + k*128
  __shared__ __align__(16) float feed[4 * 32];       // sync -> wave0 feed ring
  const int g = blockIdx.x;
  const int wv = threadIdx.x >> 6;        // 0..3 DP, 4 sync
  const int lane = threadIdx.x & 63;
  const int sb = g * 4;

  float Dcur = INF, Dul = INF;
  int fchk = 0, fpend = 0;
  float rfeed = INF;
  const float* bin = bound + (size_t)(sb > 0 ? sb - 1 : 0) * IL;
  float* bout3 = bound + (size_t)(sb + 3) * IL;

  // per-DP-wave global base for this strip (lane-major layout); block b at +b*256 uint4
  const uint4* cbase4 = (const uint4*)((const uint_t*)c_h +
      (size_t)(sb + (wv < 4 ? wv : 0)) * (SSH / 2) + lane * 16);

  uint4 Pb[4], Qb[4];

  // ---- pre-loop ----
  if (wv < 4) {
    Pb[0] = cbase4[0]; Pb[1] = cbase4[1]; Pb[2] = cbase4[2]; Pb[3] = cbase4[3];
    if (g == 0 && wv == 0 && lane == 0) Dcur = 0.f;
  } else {
    if (g > 0) {
      int f;
      do { f = __hip_atomic_load(&flags[sb - 1], __ATOMIC_RELAXED, __HIP_MEMORY_SCOPE_AGENT); } while (f < GATE);
      fchk = f; fpend = f;
      if (lane < 32) {
        feed[lane]      = __hip_atomic_load(&bin[lane],      __ATOMIC_RELAXED, __HIP_MEMORY_SCOPE_AGENT);
        feed[32 + lane] = __hip_atomic_load(&bin[32 + lane], __ATOMIC_RELAXED, __HIP_MEMORY_SCOPE_AGENT);
        rfeed           = __hip_atomic_load(&bin[64 + lane], __ATOMIC_RELAXED, __HIP_MEMORY_SCOPE_AGENT);
      }
    } else {
      if (lane < 32) { feed[lane] = INF; feed[32+lane] = INF; feed[64+lane] = INF; feed[96+lane] = INF; }
    }
  }
  __syncthreads();   // full drain once; Pb resident, feed initialized

  auto body = [&](int i, uint4 (&cur)[4], uint4 (&nxt)[4]) {
    if (wv < 4) {
      // ---- DP wave k = wv, strip sb+k, block W = i - 3k (lag 3) ----
      const int W = i - 3 * wv;
      int Wn = W + 1; Wn = Wn < 0 ? 0 : (Wn > NB - 1 ? NB - 1 : Wn);
      const uint4* sp = cbase4 + (size_t)Wn * 256;
      if (W >= 0 && W < NB) {
        // (1) boundary values: fv[tt] = boundary for col 32W+tt
        const float* fb = (wv == 0) ? &feed[(W & 3) * 32]
                                    : &ring[(wv - 1) * 128 + (W & 3) * 32];
        float fv[32];
        #pragma unroll
        for (int q = 0; q < 8; q++) {
          float4 f4 = *(const float4*)(fb + q * 4);
          fv[4 * q]     = f4.x; fv[4 * q + 1] = f4.y;
          fv[4 * q + 2] = f4.z; fv[4 * q + 3] = f4.w;
        }
        // (2) unpack CURRENT block from registers (waits only on prev-period loads)
        float cvv[32];
        #pragma unroll
        for (int q = 0; q < 4; q++) {
          const uint4 v = cur[q];
          union { uint_t u; _Float16 h[2]; } cu;
          cu.u = v.x; cvv[8*q+0] = (float)cu.h[0]; cvv[8*q+1] = (float)cu.h[1];
          cu.u = v.y; cvv[8*q+2] = (float)cu.h[0]; cvv[8*q+3] = (float)cu.h[1];
          cu.u = v.z; cvv[8*q+4] = (float)cu.h[0]; cvv[8*q+5] = (float)cu.h[1];
          cu.u = v.w; cvv[8*q+6] = (float)cu.h[0]; cvv[8*q+7] = (float)cu.h[1];
        }
        // (3) NOW issue depth-1 prefetch of block W+1 (consumed next body)
        nxt[0] = sp[0]; nxt[1] = sp[1]; nxt[2] = sp[2]; nxt[3] = sp[3];
        // (4) the recurrence chain (exact R5 single-step)
        float bb[32];                       // lane63's per-step Dcur (SSA aliases)
        if (W >= 2 && W < 256) {
          #pragma unroll
          for (int tt = 0; tt < 32; tt++) {
            float Dup = dpp_wave_shr1(fv[tt], Dcur);  // lane0 hole <- boundary col 32W+tt
            float m1 = fminf(Dul, Dcur);              // parallel with dpp
            Dcur = cvv[tt] + fminf(m1, Dup);
            Dul = Dup;
            bb[tt] = Dcur;
          }
        } else {
          const int t0 = W * 32;
          #pragma unroll
          for (int tt = 0; tt < 32; tt++) {
            const int t = t0 + tt;
            float Dup = dpp_wave_shr1(fv[tt], Dcur);
            float m1 = fminf(Dul, Dcur);
            float Dnew = cvv[tt] + fminf(m1, Dup);
            const bool alo = (t >= lane);          // j >= 0
            const bool ahi = (t - lane < IL);      // j < IL
            if (alo) Dul = Dup;
            if (alo && ahi) Dcur = Dnew;
            bb[tt] = Dcur;
          }
        }
        // (5) ring write: lane63's bottom-row values (verified mapping:
        // step tt -> col 32(W-2)+tt+1 -> slot W-2 pos tt+1 (tt<=30, W>=2);
        // tt=31 -> slot W-1 pos 0 (W>=1))
        if (lane == 63) {
          const int base2 = wv * 128 + (((W - 2) & 3) << 5);
          const int base1 = wv * 128 + (((W - 1) & 3) << 5);
          if (W >= 2) {
            #pragma unroll
            for (int tt = 0; tt < 31; tt++) ring[base2 + tt + 1] = bb[tt];
          }
          if (W >= 1) ring[base1] = bb[31];
        }
      } else {
        // out-of-range: still stage (clamped) so nxt is defined for next body
        nxt[0] = sp[0]; nxt[1] = sp[1]; nxt[2] = sp[2]; nxt[3] = sp[3];
      }
      asm volatile("s_waitcnt lgkmcnt(0)" ::: "memory");  // ring writes visible
      __builtin_amdgcn_s_barrier();
    } else {
      // ---- sync wave ----
      asm volatile("s_waitcnt vmcnt(0)" ::: "memory");    // prev-iter ops (one period old)
      if (g > 0) {
        if (fpend > fchk) fchk = fpend;           // consume last iter's flag load
        const int Fw = i + 2;                     // ds_write feed loaded last iter
        if (Fw >= 2 && Fw <= 255 && lane < 32) feed[(Fw & 3) * 32 + lane] = rfeed;
        const int Fl = i + 3;                     // issue next feed load
        if (Fl <= 255) {
          const int need = 32 * (Fl + 1);
          if (fchk < need) {                      // rare (cushion covers steady state)
            int f;
            do { f = __hip_atomic_load(&flags[sb - 1], __ATOMIC_RELAXED, __HIP_MEMORY_SCOPE_AGENT); } while (f < need);
            fchk = f;
          }
          if (lane < 32)
            rfeed = __hip_atomic_load(&bin[32 * Fl + lane], __ATOMIC_RELAXED, __HIP_MEMORY_SCOPE_AGENT);
        }
        fpend = __hip_atomic_load(&flags[sb - 1], __ATOMIC_RELAXED, __HIP_MEMORY_SCOPE_AGENT);
      }
      if (g < 3) {
        const int E = i - 12;                     // export wave3's boundary block E
        if (E >= 0 && E < 256 && lane < 32) {
          float bv2 = ring[3 * 128 + (E & 3) * 32 + lane];
          __hip_atomic_store(&bout3[32 * E + lane], bv2, __ATOMIC_RELAXED, __HIP_MEMORY_SCOPE_AGENT);
        }
        const int Ep = i - 13;                    // publish E-1's export (drained at iter start)
        if (Ep >= 0 && Ep < 256 && lane == 0)
          __hip_atomic_store(&flags[sb + 3], 32 * Ep + 32, __ATOMIC_RELAXED, __HIP_MEMORY_SCOPE_AGENT);
      }
      asm volatile("s_waitcnt lgkmcnt(0)" ::: "memory");  // publish feed ds_write
      __builtin_amdgcn_s_barrier();
    }
  };

  for (int i = 0; i < NIT2; i += 2) {
    body(i, Pb, Qb);
    body(i + 1, Qb, Pb);
  }

  asm volatile("s_waitcnt vmcnt(0)" ::: "memory");  // quiesce before endpgm
  if (g == 3 && wv == 3 && lane == 63) out[0] = Dcur;  // D[K-1][I-1] == optimal path sum
}

extern "C" void kernel_launch(void* const* d_in, const int* in_sizes, int n_in,
                              void* d_out, int out_size, void* d_ws, size_t ws_size,
                              hipStream_t stream) {
  const float* kern = (const float*)d_in[0]; // (1024,128)
  const float* xx   = (const float*)d_in[1]; // (8192,128)
  char* ws = (char*)d_ws;
  const size_t OFF_X2 = (size_t)NS * SSH * 2;           // c_h: ~16.9 MB
  const size_t OFF_K2 = OFF_X2 + (size_t)IL * 4;
  const size_t OFF_BD = OFF_K2 + (size_t)KL * 4;
  const size_t OFF_FL = OFF_BD + (size_t)NS * IL * 4;
  ushort_t* c_h  = (ushort_t*)ws;
  float* x2    = (float*)(ws + OFF_X2);
  float* k2    = (float*)(ws + OFF_K2);
  float* bnd   = (float*)(ws + OFF_BD);
  int*   flags = (int*)(ws + OFF_FL);

  knorms<<<(IL + KL) / 4, 256, 0, stream>>>(kern, xx, x2, k2, flags);
  kgemm<<<dim3(IL / 64, NS), 256, 0, stream>>>(kern, xx, x2, k2, c_h);
  kdp<<<4, 320, 0, stream>>>(c_h, bnd, flags, (float*)d_out);
}

// Round 9
// 427.152 us; speedup vs baseline: 1.6107x; 1.0419x over previous
//
#include <hip/hip_runtime.h>
#include <hip/hip_bf16.h>

typedef unsigned short ushort_t;
typedef unsigned int uint_t;

#define KL 1024
#define IL 8192
#define DIMV 128
#define NS 16
#define NB 258               // 32-col blocks per strip
#define NP 129               // block PAIRS per strip (64 cols each)
#define NIT2 140             // wave3 ends pair 128 at i=137; export 127 at 138; publish at 139
#define SSH (8256*64)        // ushorts per strip of c_h (fp16, pair-packed)
#define GATE 512             // cross-wg start cushion in columns (8 pairs)
#define INF __builtin_inff()

typedef __attribute__((ext_vector_type(8))) short v8s;   // bf16x8 MFMA A/B frag
typedef __attribute__((ext_vector_type(4))) float v4f;   // MFMA C/D frag

// ---------------- kernel 1: squared row norms + zero flags ----------------
__global__ __launch_bounds__(256) void knorms(
    const float* __restrict__ kern, const float* __restrict__ xx,
    float* __restrict__ x2, float* __restrict__ k2, int* __restrict__ flags) {
  if (blockIdx.x == 0 && threadIdx.x < NS) flags[threadIdx.x] = 0;
  const int lane = threadIdx.x & 63;
  const int row = blockIdx.x * 4 + (threadIdx.x >> 6);
  const float* src;
  float* dst;
  if (row < IL) { src = xx + (size_t)row * DIMV; dst = x2 + row; }
  else          { src = kern + (size_t)(row - IL) * DIMV; dst = k2 + (row - IL); }
  float2 v = *(const float2*)(src + lane * 2);
  float ss = v.x * v.x + v.y * v.y;
  #pragma unroll
  for (int off = 32; off > 0; off >>= 1) ss += __shfl_down(ss, off, 64);
  if (lane == 0) *dst = ss;
}

// ---------------- kernel 2: MFMA bf16 GEMM -> c (fp16), lane-major block layout ----
// Layout: strip s, block b (32 cols), uint index = b*1024 + lane*16 + tpl
// where lane = row-within-strip (dk), tpl = (t>>1)&15, fp16 pair select = t&1.
__device__ __forceinline__ v8s pack_bf16x8(float4 a, float4 b) {
  union { unsigned int u[4]; v8s v; } r;
  union { __hip_bfloat162 h; unsigned int u; } t;
  t.h = __float22bfloat162_rn(make_float2(a.x, a.y)); r.u[0] = t.u;
  t.h = __float22bfloat162_rn(make_float2(a.z, a.w)); r.u[1] = t.u;
  t.h = __float22bfloat162_rn(make_float2(b.x, b.y)); r.u[2] = t.u;
  t.h = __float22bfloat162_rn(make_float2(b.z, b.w)); r.u[3] = t.u;
  return r.v;
}

__global__ __launch_bounds__(256) void kgemm(
    const float* __restrict__ kern, const float* __restrict__ xx,
    const float* __restrict__ x2, const float* __restrict__ k2,
    ushort_t* __restrict__ c_h) {
  __shared__ float ctile[64 * 64];   // [n=x-col][m-swizzled]
  const int T = threadIdx.x;
  const int w = T >> 6;
  const int lane = T & 63;
  const int lo = lane & 15;
  const int hi = lane >> 4;
  const int i0 = blockIdx.x * 64;    // DTW columns (x rows)
  const int s  = blockIdx.y;         // strip
  const int kr0 = s * 64;

  v4f acc[4] = {};
  #pragma unroll
  for (int ks = 0; ks < 4; ks++) {
    const int k = ks * 32 + hi * 8;
    const float* bp = xx + (size_t)(i0 + w * 16 + lo) * DIMV + k;
    v8s bf = pack_bf16x8(*(const float4*)bp, *(const float4*)(bp + 4));
    #pragma unroll
    for (int rt = 0; rt < 4; rt++) {
      const float* ap = kern + (size_t)(kr0 + rt * 16 + lo) * DIMV + k;
      v8s af = pack_bf16x8(*(const float4*)ap, *(const float4*)(ap + 4));
      acc[rt] = __builtin_amdgcn_mfma_f32_16x16x32_bf16(af, bf, acc[rt], 0, 0, 0);
    }
  }
  const float x2v = x2[i0 + w * 16 + lo];
  const int n_local = w * 16 + lo;
  #pragma unroll
  for (int rt = 0; rt < 4; rt++) {
    float4 k2f = *(const float4*)&k2[kr0 + rt * 16 + hi * 4];
    #pragma unroll
    for (int q = 0; q < 4; q++) {
      const int m_local = rt * 16 + hi * 4 + q;
      float cval = fmaxf((&k2f.x)[q] + x2v - 2.f * acc[rt][q], 0.f);
      ctile[n_local * 64 + ((m_local + 2 * n_local) & 63)] = cval;
    }
  }
  __syncthreads();
  _Float16* ob = (_Float16*)(c_h + (size_t)s * SSH);
  #pragma unroll
  for (int q = 0; q < 32; q++) {
    int tt = w + q * 4;              // local skewed row in [0,126]
    int di = tt - lane;
    if (tt <= 126 && di >= 0 && di < 64) {
      int t = i0 + tt;
      int tp = t >> 1;
      ob[(((size_t)(tp >> 4) * 1024) + lane * 16 + (tp & 15)) * 2 + (t & 1)] =
          (_Float16)ctile[di * 64 + ((lane + 2 * di) & 63)];
    }
  }
}

// ---------------- kernel 3: 4 strips/wg, 5 waves, lag-3 pipeline, 64 cols/period ----
// This revision: each DP wave processes a PAIR of 32-col blocks per barrier period,
// amortizing the ~1300cy fixed per-period cost (fv ds_read latency + ring-write tail
// + barrier) over 2x the columns. Ring widens to 8 slots/wave (mod-8 disjoint:
// consumer reads {2V,2V+1}, producer writes {2V+4..2V+6}); feed 8 slots; export and
// flag publishing per pair. DP inner loops and per-block ring mapping are byte-identical
// to the R8-verified code, executed twice per period.
__device__ __forceinline__ float dpp_wave_shr1(float oldv, float src) {
  return __int_as_float(__builtin_amdgcn_update_dpp(
      __float_as_int(oldv), __float_as_int(src), 0x138, 0xF, 0xF, false));
}

__global__ __launch_bounds__(320, 1) void kdp(
    const ushort_t* __restrict__ c_h, float* __restrict__ bound,
    int* __restrict__ flags, float* __restrict__ out) {
  __shared__ __align__(16) float ring[4 * 8 * 32];   // wave k: ring + k*256; slot s = cols 32s..32s+31
  __shared__ __align__(16) float feed[8 * 32];       // sync -> wave0 feed ring (8 slots)
  const int g = blockIdx.x;
  const int wv = threadIdx.x >> 6;        // 0..3 DP, 4 sync
  const int lane = threadIdx.x & 63;
  const int sb = g * 4;

  float Dcur = INF, Dul = INF;
  int fchk = 0, fpend = 0;
  float rfeed = INF;
  const float* bin = bound + (size_t)(sb > 0 ? sb - 1 : 0) * IL;
  float* bout3 = bound + (size_t)(sb + 3) * IL;

  // per-DP-wave global base (lane-major layout); block b at +b*256 uint4
  const uint4* cbase4 = (const uint4*)((const uint_t*)c_h +
      (size_t)(sb + (wv < 4 ? wv : 0)) * (SSH / 2) + lane * 16);

  uint4 Pb[8], Qb[8];

  // ---- pre-loop ----
  if (wv < 4) {
    // preload pair 0 (blocks 0,1)
    #pragma unroll
    for (int q = 0; q < 4; q++) { Pb[q] = cbase4[q]; Pb[4 + q] = cbase4[256 + q]; }
    if (g == 0 && wv == 0 && lane == 0) Dcur = 0.f;
  } else {
    if (g > 0) {
      int f;
      do { f = __hip_atomic_load(&flags[sb - 1], __ATOMIC_RELAXED, __HIP_MEMORY_SCOPE_AGENT); } while (f < GATE);
      fchk = f; fpend = f;
      feed[lane]      = __hip_atomic_load(&bin[lane],       __ATOMIC_RELAXED, __HIP_MEMORY_SCOPE_AGENT);  // pair 0
      feed[64 + lane] = __hip_atomic_load(&bin[64 + lane],  __ATOMIC_RELAXED, __HIP_MEMORY_SCOPE_AGENT);  // pair 1
      rfeed           = __hip_atomic_load(&bin[128 + lane], __ATOMIC_RELAXED, __HIP_MEMORY_SCOPE_AGENT);  // pair 2
    } else {
      feed[lane] = INF; feed[64 + lane] = INF; feed[128 + lane] = INF; feed[192 + lane] = INF;
    }
  }
  __syncthreads();   // full drain once; Pb resident, feed initialized

  auto chain32 = [&](int W, const float (&fv)[32], const float (&cvv)[32], float (&bb)[32]) {
    if (W >= 2 && W < 256) {
      #pragma unroll
      for (int tt = 0; tt < 32; tt++) {
        float Dup = dpp_wave_shr1(fv[tt], Dcur);  // lane0 hole <- boundary col 32W+tt
        float m1 = fminf(Dul, Dcur);              // parallel with dpp
        Dcur = cvv[tt] + fminf(m1, Dup);
        Dul = Dup;
        bb[tt] = Dcur;
      }
    } else {
      const int t0 = W * 32;
      #pragma unroll
      for (int tt = 0; tt < 32; tt++) {
        const int t = t0 + tt;
        float Dup = dpp_wave_shr1(fv[tt], Dcur);
        float m1 = fminf(Dul, Dcur);
        float Dnew = cvv[tt] + fminf(m1, Dup);
        const bool alo = (t >= lane);          // j >= 0
        const bool ahi = (t - lane < IL);      // j < IL
        if (alo) Dul = Dup;
        if (alo && ahi) Dcur = Dnew;
        bb[tt] = Dcur;
      }
    }
    // ring write (verified mapping): step tt -> col 32(W-2)+tt+1 -> slot W-2 pos tt+1
    // (tt<=30, W>=2); tt=31 -> slot W-1 pos 0 (W>=1)
    if (lane == 63) {
      const int base2 = wv * 256 + (((W - 2) & 7) << 5);
      const int base1 = wv * 256 + (((W - 1) & 7) << 5);
      if (W >= 2) {
        #pragma unroll
        for (int tt = 0; tt < 31; tt++) ring[base2 + tt + 1] = bb[tt];
      }
      if (W >= 1) ring[base1] = bb[31];
    }
  };

  auto body = [&](int i, uint4 (&cur)[8], uint4 (&nxt)[8]) {
    if (wv < 4) {
      // ---- DP wave k = wv, strip sb+k, pair V = i - 3k (blocks 2V, 2V+1) ----
      const int V = i - 3 * wv;
      int Vn = V + 1; Vn = Vn < 0 ? 0 : (Vn > NP - 1 ? NP - 1 : Vn);
      const uint4* sp = cbase4 + (size_t)Vn * 512;
      if (V >= 0 && V < NP) {
        const int W0 = 2 * V;
        // (1) boundary values for both blocks: 64 consecutive floats
        const float* fb = (wv == 0) ? &feed[(V & 3) << 6]
                                    : &ring[(wv - 1) * 256 + ((V & 3) << 6)];
        float fv0[32], fv1[32];
        #pragma unroll
        for (int q = 0; q < 8; q++) {
          float4 a = *(const float4*)(fb + q * 4);
          fv0[4*q] = a.x; fv0[4*q+1] = a.y; fv0[4*q+2] = a.z; fv0[4*q+3] = a.w;
          float4 b = *(const float4*)(fb + 32 + q * 4);
          fv1[4*q] = b.x; fv1[4*q+1] = b.y; fv1[4*q+2] = b.z; fv1[4*q+3] = b.w;
        }
        // (2) unpack block W0 from registers (waits only on prev-period loads)
        float cvv0[32];
        #pragma unroll
        for (int q = 0; q < 4; q++) {
          const uint4 v = cur[q];
          union { uint_t u; _Float16 h[2]; } cu;
          cu.u = v.x; cvv0[8*q+0] = (float)cu.h[0]; cvv0[8*q+1] = (float)cu.h[1];
          cu.u = v.y; cvv0[8*q+2] = (float)cu.h[0]; cvv0[8*q+3] = (float)cu.h[1];
          cu.u = v.z; cvv0[8*q+4] = (float)cu.h[0]; cvv0[8*q+5] = (float)cu.h[1];
          cu.u = v.w; cvv0[8*q+6] = (float)cu.h[0]; cvv0[8*q+7] = (float)cu.h[1];
        }
        // (3) issue depth-1 prefetch of pair V+1 (consumed next period)
        #pragma unroll
        for (int q = 0; q < 4; q++) { nxt[q] = sp[q]; nxt[4 + q] = sp[256 + q]; }
        // (4) block W0 chain + ring write
        float bb0[32];
        chain32(W0, fv0, cvv0, bb0);
        // (5) unpack + chain block W0+1
        float cvv1[32];
        #pragma unroll
        for (int q = 0; q < 4; q++) {
          const uint4 v = cur[4 + q];
          union { uint_t u; _Float16 h[2]; } cu;
          cu.u = v.x; cvv1[8*q+0] = (float)cu.h[0]; cvv1[8*q+1] = (float)cu.h[1];
          cu.u = v.y; cvv1[8*q+2] = (float)cu.h[0]; cvv1[8*q+3] = (float)cu.h[1];
          cu.u = v.z; cvv1[8*q+4] = (float)cu.h[0]; cvv1[8*q+5] = (float)cu.h[1];
          cu.u = v.w; cvv1[8*q+6] = (float)cu.h[0]; cvv1[8*q+7] = (float)cu.h[1];
        }
        float bb1[32];
        chain32(W0 + 1, fv1, cvv1, bb1);
      } else {
        #pragma unroll
        for (int q = 0; q < 4; q++) { nxt[q] = sp[q]; nxt[4 + q] = sp[256 + q]; }
      }
      asm volatile("s_waitcnt lgkmcnt(0)" ::: "memory");  // ring writes visible
      __builtin_amdgcn_s_barrier();
    } else {
      // ---- sync wave ----
      asm volatile("s_waitcnt vmcnt(0)" ::: "memory");    // prev-iter ops (one period old)
      if (g > 0) {
        if (fpend > fchk) fchk = fpend;           // consume last iter's flag load
        const int Fw = i + 2;                     // feed pair loaded last iter
        if (Fw >= 2 && Fw <= 127) feed[((Fw & 3) << 6) + lane] = rfeed;
        const int Fl = i + 3;                     // issue next feed pair load
        if (Fl <= 127) {
          const int need = 64 * (Fl + 1);
          if (fchk < need) {                      // rare (cushion covers steady state)
            int f;
            do { f = __hip_atomic_load(&flags[sb - 1], __ATOMIC_RELAXED, __HIP_MEMORY_SCOPE_AGENT); } while (f < need);
            fchk = f;
          }
          rfeed = __hip_atomic_load(&bin[64 * Fl + lane], __ATOMIC_RELAXED, __HIP_MEMORY_SCOPE_AGENT);
        }
        fpend = __hip_atomic_load(&flags[sb - 1], __ATOMIC_RELAXED, __HIP_MEMORY_SCOPE_AGENT);
      }
      if (g < 3) {
        const int E = i - 11;                     // export wave3's boundary pair E
        if (E >= 0 && E <= 127) {
          float bv2 = ring[3 * 256 + ((E & 3) << 6) + lane];
          __hip_atomic_store(&bout3[64 * E + lane], bv2, __ATOMIC_RELAXED, __HIP_MEMORY_SCOPE_AGENT);
        }
        const int Ep = i - 12;                    // publish E-1's export (drained at iter start)
        if (Ep >= 0 && Ep <= 127 && lane == 0)
          __hip_atomic_store(&flags[sb + 3], 64 * Ep + 64, __ATOMIC_RELAXED, __HIP_MEMORY_SCOPE_AGENT);
      }
      asm volatile("s_waitcnt lgkmcnt(0)" ::: "memory");  // publish feed ds_write
      __builtin_amdgcn_s_barrier();
    }
  };

  for (int i = 0; i < NIT2; i += 2) {
    body(i, Pb, Qb);
    body(i + 1, Qb, Pb);
  }

  asm volatile("s_waitcnt vmcnt(0)" ::: "memory");  // quiesce before endpgm
  if (g == 3 && wv == 3 && lane == 63) out[0] = Dcur;  // D[K-1][I-1] == optimal path sum
}

extern "C" void kernel_launch(void* const* d_in, const int* in_sizes, int n_in,
                              void* d_out, int out_size, void* d_ws, size_t ws_size,
                              hipStream_t stream) {
  const float* kern = (const float*)d_in[0]; // (1024,128)
  const float* xx   = (const float*)d_in[1]; // (8192,128)
  char* ws = (char*)d_ws;
  const size_t OFF_X2 = (size_t)NS * SSH * 2;           // c_h: ~16.9 MB
  const size_t OFF_K2 = OFF_X2 + (size_t)IL * 4;
  const size_t OFF_BD = OFF_K2 + (size_t)KL * 4;
  const size_t OFF_FL = OFF_BD + (size_t)NS * IL * 4;
  ushort_t* c_h  = (ushort_t*)ws;
  float* x2    = (float*)(ws + OFF_X2);
  float* k2    = (float*)(ws + OFF_K2);
  float* bnd   = (float*)(ws + OFF_BD);
  int*   flags = (int*)(ws + OFF_FL);

  knorms<<<(IL + KL) / 4, 256, 0, stream>>>(kern, xx, x2, k2, flags);
  kgemm<<<dim3(IL / 64, NS), 256, 0, stream>>>(kern, xx, x2, k2, c_h);
  kdp<<<4, 320, 0, stream>>>(c_h, bnd, flags, (float*)d_out);
}